// Round 1
// baseline (6792.431 us; speedup 1.0000x reference)
//
#include <hip/hip_runtime.h>
#include <hip/hip_bf16.h>

#define D_MODEL 1024
#define N_HEAD  16
#define D_K     64
#define MAX_LEN 1000
#define B_      4
#define S_      1000
#define M_ROWS  (B_ * S_)          // 4000
#define LN_EPS  1e-5f
#define SCALE   0.125f             // 1/sqrt(64)

// ---------------- LayerNorm: one block per row of 1024 ----------------
__global__ void ln_kernel(const float* __restrict__ x, const float* __restrict__ g,
                          const float* __restrict__ beta, float* __restrict__ y) {
    int r = blockIdx.x;
    const float* xr = x + (size_t)r * D_MODEL;
    float* yr = y + (size_t)r * D_MODEL;
    int tid = threadIdx.x;

    float v[4];
    float s = 0.f, sq = 0.f;
#pragma unroll
    for (int l = 0; l < 4; ++l) {
        v[l] = xr[tid + l * 256];
        s += v[l];
        sq += v[l] * v[l];
    }
    // wave reduce (64 lanes)
#pragma unroll
    for (int o = 32; o > 0; o >>= 1) {
        s += __shfl_down(s, o, 64);
        sq += __shfl_down(sq, o, 64);
    }
    __shared__ float rs[4], rq[4];
    if ((tid & 63) == 0) { rs[tid >> 6] = s; rq[tid >> 6] = sq; }
    __syncthreads();
    if (tid == 0) {
        rs[0] = rs[0] + rs[1] + rs[2] + rs[3];
        rq[0] = rq[0] + rq[1] + rq[2] + rq[3];
    }
    __syncthreads();
    float mu = rs[0] * (1.0f / D_MODEL);
    float var = rq[0] * (1.0f / D_MODEL) - mu * mu;
    float rstd = rsqrtf(var + LN_EPS);
#pragma unroll
    for (int l = 0; l < 4; ++l) {
        int c = tid + l * 256;
        yr[c] = (v[l] - mu) * rstd * g[c] + beta[c];
    }
}

// ---------------- GEMM: Y[M,N] = X[M,K] @ W[N,K]^T + bias (+resid) ----------------
// head_layout=1: store Y[r,o] -> out[((b*H + o/64)*S + i)*64 + o%64], r = b*S+i
#define BM 32
#define BN 32
#define BK 32
__global__ void gemm_xwT(const float* __restrict__ X, const float* __restrict__ W,
                         const float* __restrict__ bias, const float* __restrict__ resid,
                         float* __restrict__ Y, int M, int N, int K, int head_layout) {
    __shared__ float Xs[BM][BK + 1];
    __shared__ float Ws[BN][BK + 1];
    int tid = threadIdx.x;
    int row0 = blockIdx.y * BM, col0 = blockIdx.x * BN;
    float acc[4] = {0.f, 0.f, 0.f, 0.f};
    int tx = tid & 31;   // n in tile
    int ty = tid >> 5;   // 0..7 -> 4 rows each

    for (int k0 = 0; k0 < K; k0 += BK) {
#pragma unroll
        for (int l = 0; l < 4; ++l) {
            int e = tid + l * 256;
            int r = e >> 5, c = e & 31;
            Xs[r][c] = X[(size_t)(row0 + r) * K + k0 + c];
            Ws[r][c] = W[(size_t)(col0 + r) * K + k0 + c];
        }
        __syncthreads();
#pragma unroll
        for (int kk = 0; kk < BK; ++kk) {
            float wv = Ws[tx][kk];
#pragma unroll
            for (int mi = 0; mi < 4; ++mi)
                acc[mi] += Xs[ty * 4 + mi][kk] * wv;
        }
        __syncthreads();
    }
#pragma unroll
    for (int mi = 0; mi < 4; ++mi) {
        int r = row0 + ty * 4 + mi;
        int c = col0 + tx;
        float v = acc[mi] + bias[c];
        if (resid) v += resid[(size_t)r * N + c];
        if (head_layout) {
            int b = r / S_, i = r % S_;
            int h = c >> 6, d = c & 63;
            Y[((size_t)(b * N_HEAD + h) * S_ + i) * D_K + d] = v;
        } else {
            Y[(size_t)r * N + c] = v;
        }
    }
}

// ---------------- Attention: one block (256 thr) per (b,h,i) row ----------------
__global__ void attn_kernel(const float* __restrict__ qh, const float* __restrict__ kh,
                            const float* __restrict__ vh, const float* __restrict__ rel,
                            float* __restrict__ out) {
    int idx = blockIdx.x;              // (b*H + h)*S + i
    int i = idx % S_;
    int bh = idx / S_;                 // b*H + h
    int h = bh % N_HEAD;
    int b = bh / N_HEAD;
    int tid = threadIdx.x;

    __shared__ float qrow[D_K];
    __shared__ float sc[S_];
    __shared__ float red[8];
    __shared__ float part[4][D_K];

    const float* qp = qh + ((size_t)bh * S_ + i) * D_K;
    if (tid < D_K) qrow[tid] = qp[tid];
    __syncthreads();

    const float* kbase = kh + (size_t)bh * S_ * D_K;
    const float* relbase = rel + (size_t)(MAX_LEN - 1 + i) * D_K;  // row for j: -j*D_K

    for (int j = tid; j < S_; j += 256) {
        const float* kr = kbase + (size_t)j * D_K;
        const float* rr = relbase - (size_t)j * D_K;
        float acc = 0.f;
#pragma unroll
        for (int d = 0; d < D_K; ++d) acc += qrow[d] * (kr[d] + rr[d]);
        sc[j] = acc * SCALE;
    }
    __syncthreads();

    // block max
    float m = -1e30f;
    for (int j = tid; j < S_; j += 256) m = fmaxf(m, sc[j]);
#pragma unroll
    for (int o = 32; o > 0; o >>= 1) m = fmaxf(m, __shfl_down(m, o, 64));
    if ((tid & 63) == 0) red[tid >> 6] = m;
    __syncthreads();
    if (tid == 0) red[0] = fmaxf(fmaxf(red[0], red[1]), fmaxf(red[2], red[3]));
    __syncthreads();
    m = red[0];

    // exp + sum
    float s = 0.f;
    for (int j = tid; j < S_; j += 256) {
        float e = __expf(sc[j] - m);
        sc[j] = e;
        s += e;
    }
#pragma unroll
    for (int o = 32; o > 0; o >>= 1) s += __shfl_down(s, o, 64);
    if ((tid & 63) == 0) red[4 + (tid >> 6)] = s;
    __syncthreads();
    if (tid == 0) red[4] = red[4] + red[5] + red[6] + red[7];
    __syncthreads();
    float inv = 1.0f / red[4];

    // PV: 4 j-groups x 64 dims
    int d = tid & 63;
    int g = tid >> 6;
    const float* vbase = vh + (size_t)bh * S_ * D_K;
    float p = 0.f;
    for (int j = g; j < S_; j += 4) p += sc[j] * vbase[(size_t)j * D_K + d];
    part[g][d] = p;
    __syncthreads();
    if (tid < D_K) {
        float r2 = (part[0][tid] + part[1][tid] + part[2][tid] + part[3][tid]) * inv;
        out[((size_t)b * S_ + i) * D_MODEL + h * D_K + tid] = r2;
    }
}

extern "C" void kernel_launch(void* const* d_in, const int* in_sizes, int n_in,
                              void* d_out, int out_size, void* d_ws, size_t ws_size,
                              hipStream_t stream) {
    const float* q      = (const float*)d_in[0];
    const float* k      = (const float*)d_in[1];
    const float* v      = (const float*)d_in[2];
    const float* ln_g   = (const float*)d_in[3];
    const float* ln_b   = (const float*)d_in[4];
    const float* wq     = (const float*)d_in[5];
    const float* bq     = (const float*)d_in[6];
    const float* wk     = (const float*)d_in[7];
    const float* bk     = (const float*)d_in[8];
    const float* wv     = (const float*)d_in[9];
    const float* bv     = (const float*)d_in[10];
    const float* wo     = (const float*)d_in[11];
    const float* bo     = (const float*)d_in[12];
    const float* rel    = (const float*)d_in[13];
    float* out = (float*)d_out;

    const size_t TSZ = (size_t)M_ROWS * D_MODEL;   // 4,096,000 floats
    float* ws = (float*)d_ws;
    float* qn = ws + 0 * TSZ;
    float* kn = ws + 1 * TSZ;
    float* vn = ws + 2 * TSZ;
    float* qh = ws + 3 * TSZ;
    float* kh = ws + 4 * TSZ;
    float* vh = ws + 5 * TSZ;
    float* attn_out = qn;   // qn dead after q projection

    // 1. LayerNorm
    ln_kernel<<<M_ROWS, 256, 0, stream>>>(q, ln_g, ln_b, qn);
    ln_kernel<<<M_ROWS, 256, 0, stream>>>(k, ln_g, ln_b, kn);
    ln_kernel<<<M_ROWS, 256, 0, stream>>>(v, ln_g, ln_b, vn);

    // 2. Projections -> head layout [B,H,S,64]
    dim3 ggrid(D_MODEL / BN, M_ROWS / BM);
    gemm_xwT<<<ggrid, 256, 0, stream>>>(qn, wq, bq, nullptr, qh, M_ROWS, D_MODEL, D_MODEL, 1);
    gemm_xwT<<<ggrid, 256, 0, stream>>>(kn, wk, bk, nullptr, kh, M_ROWS, D_MODEL, D_MODEL, 1);
    gemm_xwT<<<ggrid, 256, 0, stream>>>(vn, wv, bv, nullptr, vh, M_ROWS, D_MODEL, D_MODEL, 1);

    // 3. Attention with relative position bias
    attn_kernel<<<B_ * N_HEAD * S_, 256, 0, stream>>>(qh, kh, vh, rel, attn_out);

    // 4. Output projection + bias + residual
    gemm_xwT<<<ggrid, 256, 0, stream>>>(attn_out, wo, bo, q, out, M_ROWS, D_MODEL, D_MODEL, 0);
}

// Round 4
// 352.268 us; speedup vs baseline: 19.2820x; 19.2820x over previous
//
#include <hip/hip_runtime.h>
#include <hip/hip_bf16.h>

#define D_MODEL 1024
#define N_HEAD  16
#define D_K     64
#define MAX_LEN 1000
#define B_      4
#define S_      1000
#define S_PAD   1024
#define M_PAD   (B_ * S_PAD)       // 4096
#define M_REAL  (B_ * S_)          // 4000
#define LN_EPS  1e-5f
#define SCALE   0.125f
#define REL_ROWS (2*MAX_LEN-1)     // 1999

typedef __attribute__((ext_vector_type(8))) short short8;
typedef __attribute__((ext_vector_type(4))) float f32x4;

__device__ __forceinline__ unsigned short f2b(float f) {
    unsigned u = __builtin_bit_cast(unsigned, f);
    u = (u + 0x7FFFu + ((u >> 16) & 1u)) >> 16;
    return (unsigned short)u;
}

__device__ __forceinline__ f32x4 mfma16(short8 a, short8 b, f32x4 c) {
    return __builtin_amdgcn_mfma_f32_16x16x32_bf16(a, b, c, 0, 0, 0);
}

__device__ __forceinline__ void gload_lds16(const void* g, void* l) {
    __builtin_amdgcn_global_load_lds(
        (const __attribute__((address_space(1))) unsigned int*)g,
        (__attribute__((address_space(3))) unsigned int*)l, 16, 0, 0);
}

// ---------------- fp32 -> bf16 convert ----------------
__global__ void cvt_kernel(const float* __restrict__ in, unsigned short* __restrict__ out, int n4) {
    int i = blockIdx.x * blockDim.x + threadIdx.x;
    if (i >= n4) return;
    float4 v = ((const float4*)in)[i];
    ushort4 o;
    o.x = f2b(v.x); o.y = f2b(v.y); o.z = f2b(v.z); o.w = f2b(v.w);
    ((ushort4*)out)[i] = o;
}

// ---------------- LayerNorm -> bf16, padded rows (i>=1000) zeroed ----------------
// Output row r = b*1024 + i (PADDED); input row = b*1000 + i (UNPADDED).
__global__ void ln_bf16_kernel(const float* __restrict__ x, const float* __restrict__ g,
                               const float* __restrict__ beta, unsigned short* __restrict__ y) {
    int r = blockIdx.x;            // padded row index
    int b = r >> 10, i = r & 1023;
    unsigned short* yr = y + (size_t)r * D_MODEL;
    int tid = threadIdx.x;
    if (i >= S_) {
#pragma unroll
        for (int l = 0; l < 4; ++l) yr[tid + l * 256] = 0;
        return;
    }
    const float* xr = x + ((size_t)b * S_ + i) * D_MODEL;   // UNPADDED input row
    float v[4];
    float s = 0.f, sq = 0.f;
#pragma unroll
    for (int l = 0; l < 4; ++l) {
        v[l] = xr[tid + l * 256];
        s += v[l];
        sq += v[l] * v[l];
    }
#pragma unroll
    for (int o = 32; o > 0; o >>= 1) {
        s += __shfl_down(s, o, 64);
        sq += __shfl_down(sq, o, 64);
    }
    __shared__ float rs[4], rq[4];
    if ((tid & 63) == 0) { rs[tid >> 6] = s; rq[tid >> 6] = sq; }
    __syncthreads();
    if (tid == 0) {
        rs[0] = rs[0] + rs[1] + rs[2] + rs[3];
        rq[0] = rq[0] + rq[1] + rq[2] + rq[3];
    }
    __syncthreads();
    float mu = rs[0] * (1.0f / D_MODEL);
    float var = rq[0] * (1.0f / D_MODEL) - mu * mu;
    float rstd = rsqrtf(var + LN_EPS);
#pragma unroll
    for (int l = 0; l < 4; ++l) {
        int c = tid + l * 256;
        yr[c] = f2b((v[l] - mu) * rstd * g[c] + beta[c]);
    }
}

// ---------------- bf16 MFMA GEMM: Y[m][n] = X[m,1024] @ W[n,1024]^T + bias ----------------
// MODE 0: Yb = head layout [b,h,i,d] bf16    MODE 1: Yb = transposed head [b,h,d,i] bf16
// MODE 2: Yf = fp32 [b*S_+i, 1024] + resid (unpadded rows only)
template<int MODE>
__global__ __launch_bounds__(256) void gemm_bf16(
        const unsigned short* __restrict__ X, const unsigned short* __restrict__ W,
        const float* __restrict__ bias, const float* __restrict__ resid,
        unsigned short* __restrict__ Yb, float* __restrict__ Yf) {
    __shared__ __align__(16) unsigned short As[128 * 32];
    __shared__ __align__(16) unsigned short Bs[128 * 32];
    int tid = threadIdx.x;
    int lane = tid & 63, w = tid >> 6;
    int wr = w >> 1, wc = w & 1;
    int fr = lane & 15, fk = (lane >> 4) * 8;
    int row0 = blockIdx.y * 128, col0 = blockIdx.x * 128;

    f32x4 acc[4][4];
#pragma unroll
    for (int fm = 0; fm < 4; ++fm)
#pragma unroll
        for (int fn = 0; fn < 4; ++fn) acc[fm][fn] = (f32x4)0.f;

    // staging chunks: c = (w*2+l)*64 + lane; row = c>>2, koff = (c&3)*8 ushorts
    int c0 = (w * 2 + 0) * 64 + lane;
    int c1 = (w * 2 + 1) * 64 + lane;
    const unsigned short* xs0 = X + (size_t)(row0 + (c0 >> 2)) * 1024 + (c0 & 3) * 8;
    const unsigned short* xs1 = X + (size_t)(row0 + (c1 >> 2)) * 1024 + (c1 & 3) * 8;
    const unsigned short* ws0 = W + (size_t)(col0 + (c0 >> 2)) * 1024 + (c0 & 3) * 8;
    const unsigned short* ws1 = W + (size_t)(col0 + (c1 >> 2)) * 1024 + (c1 & 3) * 8;
    unsigned short* ad0 = As + (w * 2 + 0) * 512;
    unsigned short* ad1 = As + (w * 2 + 1) * 512;
    unsigned short* bd0 = Bs + (w * 2 + 0) * 512;
    unsigned short* bd1 = Bs + (w * 2 + 1) * 512;

    for (int k0 = 0; k0 < 1024; k0 += 32) {
        gload_lds16(xs0 + k0, ad0);
        gload_lds16(xs1 + k0, ad1);
        gload_lds16(ws0 + k0, bd0);
        gload_lds16(ws1 + k0, bd1);
        __syncthreads();
        short8 a[4], b[4];
#pragma unroll
        for (int fm = 0; fm < 4; ++fm)
            a[fm] = *(const short8*)(As + (wr * 64 + fm * 16 + fr) * 32 + fk);
#pragma unroll
        for (int fn = 0; fn < 4; ++fn)
            b[fn] = *(const short8*)(Bs + (wc * 64 + fn * 16 + fr) * 32 + fk);
#pragma unroll
        for (int fm = 0; fm < 4; ++fm)
#pragma unroll
            for (int fn = 0; fn < 4; ++fn)
                acc[fm][fn] = mfma16(a[fm], b[fn], acc[fm][fn]);
        __syncthreads();
    }

#pragma unroll
    for (int fm = 0; fm < 4; ++fm) {
#pragma unroll
        for (int fn = 0; fn < 4; ++fn) {
            int cg = col0 + wc * 64 + fn * 16 + fr;
            float bv = bias[cg];
#pragma unroll
            for (int r = 0; r < 4; ++r) {
                int rg = row0 + wr * 64 + fm * 16 + (lane >> 4) * 4 + r;
                float val = acc[fm][fn][r] + bv;
                int b_ = rg >> 10, i = rg & 1023;
                if (MODE == 0) {
                    int h = cg >> 6, d = cg & 63;
                    Yb[(((size_t)(b_ * N_HEAD + h)) * S_PAD + i) * D_K + d] = f2b(val);
                } else if (MODE == 1) {
                    int h = cg >> 6, d = cg & 63;
                    Yb[(((size_t)(b_ * N_HEAD + h)) * D_K + d) * S_PAD + i] = f2b(val);
                } else {
                    // output/residual are UNPADDED: flat row = b*1000 + i
                    if (i < S_) {
                        size_t orow = (size_t)b_ * S_ + i;
                        Yf[orow * 1024 + cg] = val + resid[orow * 1024 + cg];
                    }
                }
            }
        }
    }
}

// ---------------- Flash attention with relative-position bias, bf16 MFMA ----------------
// One wave per 16-row Q slab. qh/kh: [bh][i][d] bf16, vt: [bh][d][i] bf16, relb: [1999][64] bf16.
// Output aout: [m=b*1024+i][h*64+d] bf16.
#define QRP 84
__global__ __launch_bounds__(256) void attn_mfma(
        const unsigned short* __restrict__ qh, const unsigned short* __restrict__ kh,
        const unsigned short* __restrict__ vt, const unsigned short* __restrict__ relb,
        unsigned short* __restrict__ aout) {
    __shared__ __align__(16) float QRs[4][16 * QRP];
    __shared__ __align__(16) unsigned short Ps[4][16 * 72];

    int tid = threadIdx.x, lane = tid & 63, w = tid >> 6;
    int slab = blockIdx.x * 4 + w;
    int bh = slab >> 6;
    int i0 = (slab & 63) * 16;
    int fr = lane & 15, fk8 = (lane >> 4) * 8, rgrp = (lane >> 4) * 4;

    // Q fragments (reused for QK and Q-rel): rows i0+fr, k halves 0/1
    const unsigned short* qp = qh + ((size_t)bh * S_PAD + i0 + fr) * D_K + fk8;
    short8 aq0 = *(const short8*)(qp);
    short8 aq1 = *(const short8*)(qp + 32);

    f32x4 accO[4];
#pragma unroll
    for (int fd = 0; fd < 4; ++fd) accO[fd] = (f32x4)0.f;
    float mrun[4], lrun[4];
#pragma unroll
    for (int r = 0; r < 4; ++r) { mrun[r] = -3e38f; lrun[r] = 0.f; }

    float* qrs = QRs[w];
    unsigned short* ps = Ps[w];

    for (int jt = 0; jt < 16; ++jt) {
        int j0 = jt * 64;
        // ---- QK^T: 4 col-fragments x 2 k-steps ----
        f32x4 accS[4];
#pragma unroll
        for (int fj = 0; fj < 4; ++fj) accS[fj] = (f32x4)0.f;
#pragma unroll
        for (int fj = 0; fj < 4; ++fj) {
            const unsigned short* kp = kh + ((size_t)bh * S_PAD + j0 + fj * 16 + fr) * D_K + fk8;
            accS[fj] = mfma16(aq0, *(const short8*)(kp), accS[fj]);
            accS[fj] = mfma16(aq1, *(const short8*)(kp + 32), accS[fj]);
        }
        // ---- Q @ relband^T: band cols 0..79 cover u = ub..ub+79 ----
        int ub = i0 - j0 + (S_ - D_K);  // i0 - j0 + 936
        f32x4 qr[5];
#pragma unroll
        for (int fu = 0; fu < 5; ++fu) qr[fu] = (f32x4)0.f;
#pragma unroll
        for (int fu = 0; fu < 5; ++fu) {
            int u = ub + fu * 16 + fr;
            u = u < 0 ? 0 : (u > REL_ROWS - 1 ? REL_ROWS - 1 : u);
            const unsigned short* rp = relb + (size_t)u * D_K + fk8;
            qr[fu] = mfma16(aq0, *(const short8*)(rp), qr[fu]);
            qr[fu] = mfma16(aq1, *(const short8*)(rp + 32), qr[fu]);
        }
        // spill QR to LDS (wave-local) for the diagonal gather
#pragma unroll
        for (int fu = 0; fu < 5; ++fu)
#pragma unroll
            for (int r = 0; r < 4; ++r)
                qrs[(rgrp + r) * QRP + fu * 16 + fr] = qr[fu][r];

        // ---- assemble scores, row-max ----
        float sc[4][4];
        float pm[4];
#pragma unroll
        for (int r = 0; r < 4; ++r) pm[r] = -3e38f;
#pragma unroll
        for (int fj = 0; fj < 4; ++fj) {
            int j_loc = fj * 16 + fr;
            bool valid = (j0 + j_loc) < S_;
#pragma unroll
            for (int r = 0; r < 4; ++r) {
                int col = rgrp + r - j_loc + 63;  // in [0,78]
                float v = (accS[fj][r] + qrs[(rgrp + r) * QRP + col]) * SCALE;
                sc[fj][r] = valid ? v : -3e38f;
                pm[r] = fmaxf(pm[r], sc[fj][r]);
            }
        }
#pragma unroll
        for (int mask = 1; mask <= 8; mask <<= 1)
#pragma unroll
            for (int r = 0; r < 4; ++r)
                pm[r] = fmaxf(pm[r], __shfl_xor(pm[r], mask, 64));

        // ---- online softmax update ----
        float scl[4], rsum[4];
#pragma unroll
        for (int r = 0; r < 4; ++r) {
            float mn = fmaxf(mrun[r], pm[r]);
            scl[r] = __expf(mrun[r] - mn);
            mrun[r] = mn;
            rsum[r] = 0.f;
        }
#pragma unroll
        for (int fj = 0; fj < 4; ++fj)
#pragma unroll
            for (int r = 0; r < 4; ++r) {
                float p = __expf(sc[fj][r] - mrun[r]);
                rsum[r] += p;
                ps[(rgrp + r) * 72 + fj * 16 + fr] = f2b(p);
            }
#pragma unroll
        for (int mask = 1; mask <= 8; mask <<= 1)
#pragma unroll
            for (int r = 0; r < 4; ++r)
                rsum[r] += __shfl_xor(rsum[r], mask, 64);
#pragma unroll
        for (int r = 0; r < 4; ++r) lrun[r] = lrun[r] * scl[r] + rsum[r];
#pragma unroll
        for (int fd = 0; fd < 4; ++fd)
#pragma unroll
            for (int r = 0; r < 4; ++r) accO[fd][r] *= scl[r];

        // ---- PV: A = P (from LDS), B = V^T fragments from vt ----
        short8 ap0 = *(const short8*)(ps + fr * 72 + fk8);
        short8 ap1 = *(const short8*)(ps + fr * 72 + 32 + fk8);
#pragma unroll
        for (int fd = 0; fd < 4; ++fd) {
            const unsigned short* vp = vt + ((size_t)bh * D_K + fd * 16 + fr) * S_PAD + j0 + fk8;
            accO[fd] = mfma16(ap0, *(const short8*)(vp), accO[fd]);
            accO[fd] = mfma16(ap1, *(const short8*)(vp + 32), accO[fd]);
        }
    }

    // ---- normalize + store (bf16, [m][1024] layout, padded rows included) ----
    int b_ = bh >> 4, h = bh & 15;
#pragma unroll
    for (int r = 0; r < 4; ++r) {
        float inv = 1.0f / lrun[r];
        int m = b_ * S_PAD + i0 + rgrp + r;
#pragma unroll
        for (int fd = 0; fd < 4; ++fd) {
            int c = h * D_K + fd * 16 + fr;
            aout[(size_t)m * D_MODEL + c] = f2b(accO[fd][r] * inv);
        }
    }
}

extern "C" void kernel_launch(void* const* d_in, const int* in_sizes, int n_in,
                              void* d_out, int out_size, void* d_ws, size_t ws_size,
                              hipStream_t stream) {
    const float* q    = (const float*)d_in[0];
    const float* k    = (const float*)d_in[1];
    const float* v    = (const float*)d_in[2];
    const float* ln_g = (const float*)d_in[3];
    const float* ln_b = (const float*)d_in[4];
    const float* wq   = (const float*)d_in[5];
    const float* bq   = (const float*)d_in[6];
    const float* wk   = (const float*)d_in[7];
    const float* bk   = (const float*)d_in[8];
    const float* wv   = (const float*)d_in[9];
    const float* bv   = (const float*)d_in[10];
    const float* wo   = (const float*)d_in[11];
    const float* bo   = (const float*)d_in[12];
    const float* rel  = (const float*)d_in[13];
    float* out = (float*)d_out;

    const size_t TSZ = (size_t)M_PAD * D_MODEL;     // 4,194,304 ushorts
    unsigned short* ws   = (unsigned short*)d_ws;
    unsigned short* qn   = ws;
    unsigned short* kn   = qn + TSZ;
    unsigned short* vn   = kn + TSZ;
    unsigned short* qh   = vn + TSZ;
    unsigned short* kh   = qh + TSZ;
    unsigned short* vt   = kh + TSZ;
    unsigned short* aout = vt + TSZ;
    unsigned short* wqb  = aout + TSZ;
    unsigned short* wkb  = wqb + 1024 * 1024;
    unsigned short* wvb  = wkb + 1024 * 1024;
    unsigned short* wob  = wvb + 1024 * 1024;
    unsigned short* relb = wob + 1024 * 1024;

    // weight / rel conversions to bf16
    cvt_kernel<<<1024, 256, 0, stream>>>(wq, wqb, 262144);
    cvt_kernel<<<1024, 256, 0, stream>>>(wk, wkb, 262144);
    cvt_kernel<<<1024, 256, 0, stream>>>(wv, wvb, 262144);
    cvt_kernel<<<1024, 256, 0, stream>>>(wo, wob, 262144);
    cvt_kernel<<<125, 256, 0, stream>>>(rel, relb, REL_ROWS * D_K / 4);

    // LayerNorms (padded to 4096 rows, unpadded input reads)
    ln_bf16_kernel<<<M_PAD, 256, 0, stream>>>(q, ln_g, ln_b, qn);
    ln_bf16_kernel<<<M_PAD, 256, 0, stream>>>(k, ln_g, ln_b, kn);
    ln_bf16_kernel<<<M_PAD, 256, 0, stream>>>(v, ln_g, ln_b, vn);

    // projections
    dim3 g8(8, 32);
    gemm_bf16<0><<<g8, 256, 0, stream>>>(qn, wqb, bq, nullptr, qh, nullptr);
    gemm_bf16<0><<<g8, 256, 0, stream>>>(kn, wkb, bk, nullptr, kh, nullptr);
    gemm_bf16<1><<<g8, 256, 0, stream>>>(vn, wvb, bv, nullptr, vt, nullptr);

    // fused attention
    attn_mfma<<<1024, 256, 0, stream>>>(qh, kh, vt, relb, aout);

    // output projection + bias + residual
    gemm_bf16<2><<<g8, 256, 0, stream>>>(aout, wob, bo, q, nullptr, out);
}